// Round 18
// baseline (405.100 us; speedup 1.0000x reference)
//
#include <hip/hip_runtime.h>

// out[b] = ||xd_b||^2 - (s_b . xd_b)^2 / (1 + ||s_b||^2), s = x @ W^T.
// R18: MX-fp4 (e2m1), fixed scales=1.0, W x64 (finalize /(4096+ns)).
// NO LDS, NO BARRIERS. R17 made both operand panels L2-resident; LDS staging
// was only adding the 16-iteration barrier lattice (the measured ~3x residue
// every schedule/TLP/latency probe failed to remove). Cast now writes x,W in
// fragment-major tiled layout: chunk(rowblk,kchunk) = 256 B = [fr 16][16 B],
// so one coalesced global_load_dwordx4 per fragment straight from L2.
// K-loop: 8 loads + 16 MFMA per kt, manual unroll-2 with two static register
// sets (one-kt-ahead prefetch; compiler emits counted vmcnt). Waves fully
// independent. Geometry/XCD-remap/epilogue identical to R17 (128^2 tile,
// 4 waves 2x2, acc[4][4], XCD k owns brow panels [16k,16k+16)).

#define MTOT 16384
#define DTOT 2048
#define NK 16   // K-tiles of 128

typedef unsigned char u8;
typedef __attribute__((ext_vector_type(4))) float f32x4;
typedef __attribute__((ext_vector_type(8))) int i32x8;

// f32 -> OCP e2m1 (fp4), RNE, saturating. Values {0,.5,1,1.5,2,3,4,6}.
__device__ __forceinline__ unsigned f2e2m1(float f) {
    unsigned sgn = f < 0.f ? 8u : 0u;
    float a = fabsf(f);
    unsigned c;
    if      (a < 0.25f) c = 0;
    else if (a < 0.75f) c = 1;
    else if (a < 1.25f) c = 2;
    else if (a < 1.75f) c = 3;
    else if (a < 2.5f)  c = 4;
    else if (a < 3.5f)  c = 5;
    else if (a < 5.0f)  c = 6;
    else                c = 7;
    return sgn | c;
}

// ---- cast f32 -> fp4, fragment-major tiled layout ----
// dst chunk j (16 B): rowblk = j>>10, kchunk = (j>>4)&63, fr = j&15.
// Holds row = rowblk*16+fr, kcols [kchunk*32, kchunk*32+32) as 32 nibbles.
// Writes perfectly coalesced (consecutive j -> consecutive 16 B).
__global__ void cast4t_kernel(const float* __restrict__ src, uint4* __restrict__ dst,
                              int nchunks, float mul) {
    int stride = gridDim.x * blockDim.x;
    for (int j = blockIdx.x * blockDim.x + threadIdx.x; j < nchunks; j += stride) {
        const int rowblk = j >> 10, kchunk = (j >> 4) & 63, fr = j & 15;
        const int row = rowblk * 16 + fr;
        const f32x4* p = (const f32x4*)(src + (size_t)row * DTOT + kchunk * 32);
        unsigned w[4];
#pragma unroll
        for (int q = 0; q < 4; ++q) {
            f32x4 v0 = p[2 * q], v1 = p[2 * q + 1];
            w[q] =  f2e2m1(v0[0] * mul)        | (f2e2m1(v0[1] * mul) << 4)  |
                   (f2e2m1(v0[2] * mul) << 8)  | (f2e2m1(v0[3] * mul) << 12) |
                   (f2e2m1(v1[0] * mul) << 16) | (f2e2m1(v1[1] * mul) << 20) |
                   (f2e2m1(v1[2] * mul) << 24) | (f2e2m1(v1[3] * mul) << 28);
        }
        dst[j] = make_uint4(w[0], w[1], w[2], w[3]);
    }
}

// ---------------- fp4 128^2 GEMM, L2-direct, barrier-free ----------------
// grid = 2048 blocks x 256 threads (4 waves, 2x2, wave tile 64x64, acc[4][4]).
// One mfma_scale_16x16x128 (FMT=4) per frag per kt.
// Fragment address (tiled layout): chunk(rowblk, kt*4+fq) + fr*16, stepping
// 1024 B per kt. 8 coalesced b128 loads + 16 MFMA per kt; two register sets
// alternate (A-set even kt, B-set odd kt), prefetch issued one kt ahead.
// XCD map (R17): XCD k = bid%8 owns brow panels [16k,16k+16); bcol slowest.
__global__ __launch_bounds__(256, 3)
void gemmf4(const u8* __restrict__ xqt, const u8* __restrict__ wqt,
            const float* __restrict__ xdot,
            float* __restrict__ ns_acc, float* __restrict__ sx_acc,
            float* __restrict__ xx_acc) {
    const int tid  = threadIdx.x;
    const int lane = tid & 63;
    const int wid  = tid >> 6;
    const int wr = wid >> 1, wc = wid & 1;   // 2 x 2 wave grid
    const int fr = lane & 15, fq = lane >> 4;

    const int bid = blockIdx.x;              // 2048
    const int brow = ((bid & 7) * 16 + ((bid >> 3) & 15)) * 128;
    const int bcol = (bid >> 7) * 128;

    // per-lane fragment pointers; chunk = (rowblk*64 + kchunk)*256 B
    const u8* pA[4];
    const u8* pB[4];
#pragma unroll
    for (int m = 0; m < 4; ++m)
        pA[m] = xqt + (size_t)(((brow >> 4) + wr * 4 + m) * 64 + fq) * 256 + fr * 16;
#pragma unroll
    for (int n = 0; n < 4; ++n)
        pB[n] = wqt + (size_t)(((bcol >> 4) + wc * 4 + n) * 64 + fq) * 256 + fr * 16;

    auto mk8 = [](int4 v) -> i32x8 {
        i32x8 r;
        r[0] = v.x; r[1] = v.y; r[2] = v.z; r[3] = v.w;
        r[4] = 0;   r[5] = 0;   r[6] = 0;   r[7] = 0;
        return r;
    };

    f32x4 acc[4][4] = {};
    int4 aA[4], bA[4], aB[4], bB[4];   // two static register sets (rule #20)

    // preload kt=0 into set A
#pragma unroll
    for (int m = 0; m < 4; ++m) aA[m] = *(const int4*)(pA[m]);
#pragma unroll
    for (int n = 0; n < 4; ++n) bA[n] = *(const int4*)(pB[n]);

#pragma unroll
    for (int t = 0; t < NK; t += 2) {
        // issue kt = t+1 into set B (clamped at tail: reloads t, harmless)
        const int o1 = (t + 1 < NK ? t + 1 : t) * 1024;
#pragma unroll
        for (int m = 0; m < 4; ++m) aB[m] = *(const int4*)(pA[m] + o1);
#pragma unroll
        for (int n = 0; n < 4; ++n) bB[n] = *(const int4*)(pB[n] + o1);
        // MFMA on set A (kt = t)
        __builtin_amdgcn_s_setprio(1);
#pragma unroll
        for (int m = 0; m < 4; ++m)
#pragma unroll
            for (int n = 0; n < 4; ++n)
                acc[m][n] = __builtin_amdgcn_mfma_scale_f32_16x16x128_f8f6f4(
                    mk8(aA[m]), mk8(bA[n]), acc[m][n],
                    4, 4, 0, 0x7f7f7f7f, 0, 0x7f7f7f7f);
        __builtin_amdgcn_s_setprio(0);

        // issue kt = t+2 into set A (clamped)
        const int o2 = (t + 2 < NK ? t + 2 : t) * 1024;
#pragma unroll
        for (int m = 0; m < 4; ++m) aA[m] = *(const int4*)(pA[m] + o2);
#pragma unroll
        for (int n = 0; n < 4; ++n) bA[n] = *(const int4*)(pB[n] + o2);
        // MFMA on set B (kt = t+1)
        __builtin_amdgcn_s_setprio(1);
#pragma unroll
        for (int m = 0; m < 4; ++m)
#pragma unroll
            for (int n = 0; n < 4; ++n)
                acc[m][n] = __builtin_amdgcn_mfma_scale_f32_16x16x128_f8f6f4(
                    mk8(aB[m]), mk8(bB[n]), acc[m][n],
                    4, 4, 0, 0x7f7f7f7f, 0, 0x7f7f7f7f);
        __builtin_amdgcn_s_setprio(0);
    }

    // Epilogue (identical to R17): C/D col = lane&15, row = (lane>>4)*4 + reg.
    // Reduce s^2, s*xd, xd^2 over fr; 1 atomicAdd/row/qty/wave.
#pragma unroll
    for (int m = 0; m < 4; ++m) {
#pragma unroll
        for (int jj = 0; jj < 4; ++jj) {
            const int row = brow + wr * 64 + m * 16 + fq * 4 + jj;
            const float* xp = xdot + (size_t)row * DTOT + bcol + wc * 64 + fr;
            float pns = 0.f, psx = 0.f, pxx = 0.f;
#pragma unroll
            for (int n = 0; n < 4; ++n) {
                float s  = acc[m][n][jj];   // = 64 * s_true
                float xv = xp[n * 16];
                pns += s * s; psx += s * xv; pxx += xv * xv;
            }
#pragma unroll
            for (int msk = 1; msk < 16; msk <<= 1) {
                pns += __shfl_xor(pns, msk);
                psx += __shfl_xor(psx, msk);
                pxx += __shfl_xor(pxx, msk);
            }
            if (fr == 0) {
                atomicAdd(&ns_acc[row], pns);
                atomicAdd(&sx_acc[row], psx);
                atomicAdd(&xx_acc[row], pxx);
            }
        }
    }
}

__global__ void finalize_k(const float* __restrict__ ns, const float* __restrict__ sx,
                           const float* __restrict__ xx, float* __restrict__ out) {
    int i = blockIdx.x * blockDim.x + threadIdx.x;
    // ns,sx carry the x64 W-prescale: sx_true^2/(1+ns_true) = sx^2/(4096+ns)
    if (i < MTOT) out[i] = xx[i] - (sx[i] * sx[i]) / (4096.0f + ns[i]);
}

extern "C" void kernel_launch(void* const* d_in, const int* in_sizes, int n_in,
                              void* d_out, int out_size, void* d_ws, size_t ws_size,
                              hipStream_t stream) {
    const float* x  = (const float*)d_in[0];
    const float* xd = (const float*)d_in[1];
    const float* W  = (const float*)d_in[2];
    float* out = (float*)d_out;

    const size_t xq_bytes = (size_t)MTOT * DTOT / 2;   // 16.8 MB fp4 (tiled)
    const size_t wq_bytes = (size_t)DTOT * DTOT / 2;   //  2.1 MB fp4 (tiled)
    const size_t acc_bytes = (size_t)3 * MTOT * 4;     //  0.2 MB

    u8* xqt = (u8*)d_ws;
    u8* wqt = (u8*)((char*)d_ws + xq_bytes);
    float* accs = (float*)((char*)d_ws + xq_bytes + wq_bytes);
    float* nsA = accs;
    float* sxA = accs + MTOT;
    float* xxA = accs + 2 * MTOT;
    (void)ws_size; (void)in_sizes; (void)n_in; (void)out_size;

    hipMemsetAsync(accs, 0, acc_bytes, stream);  // re-zero every call

    cast4t_kernel<<<2048, 256, 0, stream>>>(x, (uint4*)xqt, MTOT * 64, 1.0f);
    cast4t_kernel<<<512, 256, 0, stream>>>(W, (uint4*)wqt, DTOT * 64, 64.0f);
    gemmf4<<<2048, 256, 0, stream>>>(xqt, wqt, xd, nsA, sxA, xxA);
    finalize_k<<<MTOT / 256, 256, 0, stream>>>(nsA, sxA, xxA, out);
}

// Round 19
// 158.305 us; speedup vs baseline: 2.5590x; 2.5590x over previous
//
#include <hip/hip_runtime.h>

// out[b] = ||xd_b||^2 - (s_b . xd_b)^2 / (1 + ||s_b||^2), s = x @ W^T.
// R19: MX-fp4 (e2m1), fixed scales=1.0, W x64 (finalize /(4096+ns)).
// BARRIER-FREE via 1-WAVE BLOCKS (s_barrier is a no-op with 1 wave; none
// emitted). 64x64 tile per 64-thread block, acc[4][4] (64 AGPR), LDS 16 KiB
// = 2 x {A 4KB | B 4KB} -> 10 blocks/CU, every wave at a different phase
// (m114 regime, zero rendezvous). Per kt: 8 gload_lds + 8 ds_read_b128
// (conflict-free line layout, R12/R13-verified) + 16 MFMA.
// vmcnt ledger (8 DMA/tile): prologue stage(0,1)=16, WAITV(8) -> t0 landed.
// Iter t: ds_read frags(t); LGKM0 (protects WAR: stage(t+2) hits buf(t&1));
// stage(t+2); 16 MFMA; WAITV(8) -> t+1 landed (issued a full iter ago,
// L2 latency covered), t+2 flying. Tail clamped (idempotent).
// XCD map: XCD k = bid%8 owns brow panels [32k,32k+32) (2 MB x, L2-resident);
// bcol sweeps slowest. R18's spill trap avoided: operands stay in LDS,
// only one frag set in regs (~100 arch+AGPR total).

#define MTOT 16384
#define DTOT 2048
#define NK 16   // K-tiles of 128

typedef unsigned char u8;
typedef __attribute__((ext_vector_type(4))) float f32x4;
typedef __attribute__((ext_vector_type(8))) int i32x8;

// f32 -> OCP e2m1 (fp4), RNE, saturating. Values {0,.5,1,1.5,2,3,4,6}.
__device__ __forceinline__ unsigned f2e2m1(float f) {
    unsigned sgn = f < 0.f ? 8u : 0u;
    float a = fabsf(f);
    unsigned c;
    if      (a < 0.25f) c = 0;
    else if (a < 0.75f) c = 1;
    else if (a < 1.25f) c = 2;
    else if (a < 1.75f) c = 3;
    else if (a < 2.5f)  c = 4;
    else if (a < 3.5f)  c = 5;
    else if (a < 5.0f)  c = 6;
    else                c = 7;
    return sgn | c;
}

__device__ __forceinline__ void gload_lds16(const void* gptr, void* ldsptr) {
    __builtin_amdgcn_global_load_lds(
        (const __attribute__((address_space(1))) unsigned int*)gptr,
        (__attribute__((address_space(3))) unsigned int*)ldsptr,
        16, 0, 0);
}

#define SCHED0() __builtin_amdgcn_sched_barrier(0)
#define LGKM0()  asm volatile("s_waitcnt lgkmcnt(0)")
#define WAITV(n) asm volatile("s_waitcnt vmcnt(" #n ")")

// ------------- cast f32 -> fp4, x and W in ONE launch (8 elems/thread) -------------
__global__ void cast4two_kernel(const float* __restrict__ x, const float* __restrict__ W,
                                unsigned* __restrict__ xq, unsigned* __restrict__ wq,
                                int nx8, int ntot8) {
    int stride = gridDim.x * blockDim.x;
    for (int i = blockIdx.x * blockDim.x + threadIdx.x; i < ntot8; i += stride) {
        const float* s; unsigned* d; int j; float mul;
        if (i < nx8) { s = x; d = xq; j = i; mul = 1.0f; }
        else         { s = W; d = wq; j = i - nx8; mul = 64.0f; }
        f32x4 v0 = ((const f32x4*)s)[2 * (size_t)j];
        f32x4 v1 = ((const f32x4*)s)[2 * (size_t)j + 1];
        d[j] =  f2e2m1(v0[0] * mul)        | (f2e2m1(v0[1] * mul) << 4)  |
               (f2e2m1(v0[2] * mul) << 8)  | (f2e2m1(v0[3] * mul) << 12) |
               (f2e2m1(v1[0] * mul) << 16) | (f2e2m1(v1[1] * mul) << 20) |
               (f2e2m1(v1[2] * mul) << 24) | (f2e2m1(v1[3] * mul) << 28);
    }
}

// ---------------- fp4 64^2 1-wave GEMM + fused reductions ----------------
__global__ __launch_bounds__(64, 3)
void gemmf4(const u8* __restrict__ xq, const u8* __restrict__ wq,
            const float* __restrict__ xdot,
            float* __restrict__ ns_acc, float* __restrict__ sx_acc,
            float* __restrict__ xx_acc) {
    __shared__ u8 lds[16384];   // [2 buf][A 4 KiB | B 4 KiB]

    const int lane = threadIdx.x;            // 64 threads = 1 wave
    const int fr = lane & 15, fq = lane >> 4;

    const int bid = blockIdx.x;              // 8192
    const int xcd = bid & 7, loc = bid >> 3;
    const int brow = (xcd * 32 + (loc & 31)) * 64;   // XCD-local x slice
    const int bcol = (loc >> 5) * 64;                // sweeps slowest

    const int RS = DTOT / 2;   // row stride in fp4 bytes = 1024

    // staging geometry (lane-constant): chunk c = i*64+lane, line L = c>>3,
    // phys p = c&7, logical q = p^(L&7), row = 2L+(q>>2), unit = q&3.
    int sgo[4];   // global byte offset within a 64-row panel, per chunk i
#pragma unroll
    for (int i = 0; i < 4; ++i) {
        const int c = i * 64 + lane;
        const int L = c >> 3, p = c & 7;
        const int q = p ^ (L & 7);
        sgo[i] = (2 * L + (q >> 2)) * RS + (q & 3) * 16;
    }
    const u8* xA = xq + (size_t)brow * RS;
    const u8* wB = wq + (size_t)bcol * RS;

    auto stage_tile = [&](int kt, int bufbyte) {
        const int kb = kt * 64;              // 128 k-elems = 64 B
        char* la = (char*)lds + bufbyte + lane * 16;
#pragma unroll
        for (int i = 0; i < 4; ++i) {
            gload_lds16(xA + sgo[i] + kb, la + i * 1024);
            gload_lds16(wB + sgo[i] + kb, la + 4096 + i * 1024);
        }
    };

    // frag read: one b128 = k-block fq (32 fp4) of row (16n+fr).
    // L&7 = (fr>>1) for all n -> phys slot p is a per-lane constant;
    // address = region + ((fr>>1) + 8n)*128 + p*16  (2-way folds only).
    const int pslot = (((fr & 1) << 2) | fq) ^ (fr >> 1);
    const int fbase = (fr >> 1) * 128 + pslot * 16;
    auto rdfrag = [&](int region, int n) -> int4 {
        return *(const int4*)((const char*)lds + region + fbase + n * 1024);
    };
    auto mk8 = [](int4 v) -> i32x8 {
        i32x8 r;
        r[0] = v.x; r[1] = v.y; r[2] = v.z; r[3] = v.w;
        r[4] = 0;   r[5] = 0;   r[6] = 0;   r[7] = 0;
        return r;
    };

    f32x4 acc[4][4] = {};
    int4 af[4], bf[4];

    // ---- prologue: tiles 0 and 1
    stage_tile(0, 0);
    stage_tile(1, 8192);
    WAITV(8);   // tile 0 landed; tile 1's 8 in flight
    SCHED0();

    for (int t = 0; t < NK; ++t) {
        const int buf = (t & 1) * 8192;

#pragma unroll
        for (int m = 0; m < 4; ++m) af[m] = rdfrag(buf, m);
#pragma unroll
        for (int n = 0; n < 4; ++n) bf[n] = rdfrag(buf + 4096, n);
        LGKM0();    // frags in regs; buf(t&1) now safe to overwrite
        SCHED0();
        {   // stage tile t+2 into buf(t&1) (clamped tail, idempotent)
            const int v = t + 2 > NK - 1 ? NK - 1 : t + 2;
            stage_tile(v, buf);
        }
        SCHED0();
        __builtin_amdgcn_s_setprio(1);
#pragma unroll
        for (int m = 0; m < 4; ++m)
#pragma unroll
            for (int n = 0; n < 4; ++n)
                acc[m][n] = __builtin_amdgcn_mfma_scale_f32_16x16x128_f8f6f4(
                    mk8(af[m]), mk8(bf[n]), acc[m][n],
                    4, 4,                    // cbsz = blgp = 4 -> fp4 e2m1
                    0, 0x7f7f7f7f,           // scale A = 1.0 (e8m0)
                    0, 0x7f7f7f7f);          // scale B = 1.0
        __builtin_amdgcn_s_setprio(0);
        WAITV(8);   // tile t+1 landed (issued a full iter ago); t+2 flying
        SCHED0();
    }

    // Epilogue: C/D col = lane&15, row = (lane>>4)*4 + reg (shape-determined).
    // Reduce s^2, s*xd, xd^2 over fr; 1 atomicAdd/row/qty.
#pragma unroll
    for (int m = 0; m < 4; ++m) {
#pragma unroll
        for (int jj = 0; jj < 4; ++jj) {
            const int row = brow + m * 16 + fq * 4 + jj;
            const float* xp = xdot + (size_t)row * DTOT + bcol + fr;
            float pns = 0.f, psx = 0.f, pxx = 0.f;
#pragma unroll
            for (int n = 0; n < 4; ++n) {
                float s  = acc[m][n][jj];   // = 64 * s_true
                float xv = xp[n * 16];
                pns += s * s; psx += s * xv; pxx += xv * xv;
            }
#pragma unroll
            for (int msk = 1; msk < 16; msk <<= 1) {
                pns += __shfl_xor(pns, msk);
                psx += __shfl_xor(psx, msk);
                pxx += __shfl_xor(pxx, msk);
            }
            if (fr == 0) {
                atomicAdd(&ns_acc[row], pns);
                atomicAdd(&sx_acc[row], psx);
                atomicAdd(&xx_acc[row], pxx);
            }
        }
    }
    WAITV(0);   // drain clamped tail DMA before LDS dealloc at exit
}

__global__ void finalize_k(const float* __restrict__ ns, const float* __restrict__ sx,
                           const float* __restrict__ xx, float* __restrict__ out) {
    int i = blockIdx.x * blockDim.x + threadIdx.x;
    // ns,sx carry the x64 W-prescale: sx_true^2/(1+ns_true) = sx^2/(4096+ns)
    if (i < MTOT) out[i] = xx[i] - (sx[i] * sx[i]) / (4096.0f + ns[i]);
}

extern "C" void kernel_launch(void* const* d_in, const int* in_sizes, int n_in,
                              void* d_out, int out_size, void* d_ws, size_t ws_size,
                              hipStream_t stream) {
    const float* x  = (const float*)d_in[0];
    const float* xd = (const float*)d_in[1];
    const float* W  = (const float*)d_in[2];
    float* out = (float*)d_out;

    const size_t xq_bytes = (size_t)MTOT * DTOT / 2;   // 16.8 MB fp4
    const size_t wq_bytes = (size_t)DTOT * DTOT / 2;   //  2.1 MB fp4
    const size_t acc_bytes = (size_t)3 * MTOT * 4;     //  0.2 MB

    u8* xq = (u8*)d_ws;
    u8* wq = (u8*)((char*)d_ws + xq_bytes);
    float* accs = (float*)((char*)d_ws + xq_bytes + wq_bytes);
    float* nsA = accs;
    float* sxA = accs + MTOT;
    float* xxA = accs + 2 * MTOT;
    (void)ws_size; (void)in_sizes; (void)n_in; (void)out_size;

    hipMemsetAsync(accs, 0, acc_bytes, stream);  // re-zero every call

    const int nx8 = MTOT * DTOT / 8, nw8 = DTOT * DTOT / 8;
    cast4two_kernel<<<2048, 256, 0, stream>>>(x, W, (unsigned*)xq, (unsigned*)wq,
                                              nx8, nx8 + nw8);
    gemmf4<<<8192, 64, 0, stream>>>(xq, wq, xd, nsA, sxA, xxA);
    finalize_k<<<MTOT / 256, 256, 0, stream>>>(nsA, sxA, xxA, out);
}